// Round 9
// baseline (623.197 us; speedup 1.0000x reference)
//
#include <hip/hip_runtime.h>
#include <hip/hip_cooperative_groups.h>

namespace cg = cooperative_groups;

#define C 32
#define NTC 256            // threads per coop block
#define NT 256
#define BSH 8              // 256 nodes per bucket
#define BNODE 256
#define CAPC 5632          // per-bucket capacity (mean 4096, +24 sigma)
#define SRCMASK 0x1FFFF
#define MAXBUCK 400        // >= nbuck (391)

typedef float f32x4 __attribute__((ext_vector_type(4)));

__device__ __forceinline__ unsigned int f2bf(float f) {
    unsigned int u = __float_as_uint(f);
    return (u + 0x7FFFu + ((u >> 16) & 1u)) >> 16;   // RNE to bf16
}
__device__ __forceinline__ float bflo(unsigned int u) { return __uint_as_float(u << 16); }
__device__ __forceinline__ float bfhi(unsigned int u) { return __uint_as_float(u & 0xFFFF0000u); }

// accumulate bf16 rows over pk[lo..hi) for lane-quarter lq (4 channels)
__device__ __forceinline__ void accum_seg(const uint2* __restrict__ arr,
                                          const int* __restrict__ pk,
                                          int lo, int hi, int lq,
                                          float& a0, float& a1, float& a2, float& a3) {
#define ACC4(ux, uy) { a0 += bflo(ux); a1 += bfhi(ux); a2 += bflo(uy); a3 += bfhi(uy); }
    int j = lo;
    for (; j + 7 < hi; j += 8) {
        int s0 = __builtin_nontemporal_load(&pk[j]);
        int s1 = __builtin_nontemporal_load(&pk[j + 1]);
        int s2 = __builtin_nontemporal_load(&pk[j + 2]);
        int s3 = __builtin_nontemporal_load(&pk[j + 3]);
        int s4 = __builtin_nontemporal_load(&pk[j + 4]);
        int s5 = __builtin_nontemporal_load(&pk[j + 5]);
        int s6 = __builtin_nontemporal_load(&pk[j + 6]);
        int s7 = __builtin_nontemporal_load(&pk[j + 7]);
        uint2 u0 = arr[(size_t)s0 * 8 + lq];
        uint2 u1 = arr[(size_t)s1 * 8 + lq];
        uint2 u2 = arr[(size_t)s2 * 8 + lq];
        uint2 u3 = arr[(size_t)s3 * 8 + lq];
        uint2 u4 = arr[(size_t)s4 * 8 + lq];
        uint2 u5 = arr[(size_t)s5 * 8 + lq];
        uint2 u6 = arr[(size_t)s6 * 8 + lq];
        uint2 u7 = arr[(size_t)s7 * 8 + lq];
        ACC4(u0.x, u0.y) ACC4(u1.x, u1.y) ACC4(u2.x, u2.y) ACC4(u3.x, u3.y)
        ACC4(u4.x, u4.y) ACC4(u5.x, u5.y) ACC4(u6.x, u6.y) ACC4(u7.x, u7.y)
    }
    for (; j + 1 < hi; j += 2) {
        int s0 = __builtin_nontemporal_load(&pk[j]);
        int s1 = __builtin_nontemporal_load(&pk[j + 1]);
        uint2 u0 = arr[(size_t)s0 * 8 + lq];
        uint2 u1 = arr[(size_t)s1 * 8 + lq];
        ACC4(u0.x, u0.y) ACC4(u1.x, u1.y)
    }
    if (j < hi) {
        uint2 u0 = arr[(size_t)__builtin_nontemporal_load(&pk[j]) * 8 + lq];
        ACC4(u0.x, u0.y)
    }
#undef ACC4
}

// ================= cooperative all-in-one kernel =================
__global__ __launch_bounds__(NTC) void gcn_coop(
        const float* __restrict__ x, const int* __restrict__ esrc,
        const int* __restrict__ edst, const float* __restrict__ wts,
        float* __restrict__ y, int* __restrict__ cursor,
        int* __restrict__ row_start, int* __restrict__ ideg,
        int* __restrict__ pk, float* __restrict__ t1,
        uint2* __restrict__ xb2, uint2* __restrict__ t1b2,
        int N, int E, int nbuck, int chunk) {
    cg::grid_group grid = cg::this_grid();
    __shared__ int lcnt[MAXBUCK];
    __shared__ int lcur[MAXBUCK];
    __shared__ int ent[CAPC];
    __shared__ int h[BNODE];
    __shared__ int ss[BNODE];
    __shared__ int cur[BNODE];
    int tid = threadIdx.x;
    int nb = gridDim.x;
    int gthreads = nb * NTC;
    int gid0 = blockIdx.x * NTC + tid;

    // ---- P0: zero bucket cursors ----
    for (int i = gid0; i < nbuck; i += gthreads) cursor[i] = 0;
    grid.sync();

    // ---- P1: bucketize edges by dst>>8 (reservation scheme) + fused cvt ----
    {
        for (int i = tid; i < nbuck; i += NTC) lcnt[i] = 0;
        __syncthreads();
        int base = blockIdx.x * chunk;
        int end  = min(base + chunk, E);
        for (int e = base + tid; e < end; e += NTC)
            atomicAdd(&lcnt[edst[e] >> BSH], 1);
        __syncthreads();
        for (int i = tid; i < nbuck; i += NTC) {
            int c = lcnt[i];
            lcur[i] = i * CAPC + (c ? atomicAdd(&cursor[i], c) : 0);
        }
        __syncthreads();
        for (int e = base + tid; e < end; e += NTC) {
            int d = edst[e];
            int b = d >> BSH;
            int pos = atomicAdd(&lcur[b], 1);
            pk[pos] = esrc[e] | ((d & (BNODE - 1)) << 17);
        }
        // fused x -> packed bf16 (grid-stride, independent of buckets)
        int nc8 = N * 8;
        for (int i = gid0; i < nc8; i += gthreads) {
            const float* xp = x + (size_t)i * 4;
            uint2 r;
            r.x = f2bf(xp[0]) | (f2bf(xp[1]) << 16);
            r.y = f2bf(xp[2]) | (f2bf(xp[3]) << 16);
            xb2[i] = r;
        }
    }
    grid.sync();

    // ---- P2: per-bucket counting sort (grid-stride over buckets) ----
    for (int b = blockIdx.x; b < nbuck; b += nb) {
        int base = b * CAPC;
        int cnt = min(cursor[b], CAPC);
        for (int i = tid; i < cnt; i += NTC) ent[i] = pk[base + i];
        if (tid < BNODE) h[tid] = 0;
        __syncthreads();
        for (int i = tid; i < cnt; i += NTC) atomicAdd(&h[ent[i] >> 17], 1);
        __syncthreads();
        int v = 0;
        if (tid < BNODE) { v = h[tid]; ss[tid] = v; }
        __syncthreads();
        for (int off = 1; off < BNODE; off <<= 1) {
            int u = 0;
            if (tid < BNODE && tid >= off) u = ss[tid - off];
            __syncthreads();
            if (tid < BNODE) ss[tid] += u;
            __syncthreads();
        }
        if (tid < BNODE) {
            int exc = ss[tid] - v;
            int n = (b << BSH) + tid;
            if (n < N) { row_start[n] = base + exc; ideg[n] = v; }
            cur[tid] = exc;
        }
        __syncthreads();
        for (int i = tid; i < cnt; i += NTC) {
            int en = ent[i];
            int pos = atomicAdd(&cur[en >> 17], 1);
            pk[base + pos] = en & SRCMASK;
        }
        __syncthreads();
    }
    grid.sync();

    // ---- P3: matvec1  t1 = deg*x - A@x  (8 lanes/node) ----
    int total = N * 8;
    for (int g = gid0; g < total; g += gthreads) {
        int n = g >> 3;
        int lq = g & 7;
        int rs = row_start[n];
        int dg = ideg[n];
        float a0 = 0.f, a1 = 0.f, a2 = 0.f, a3 = 0.f;
        accum_seg(xb2, pk, rs, rs + dg, lq, a0, a1, a2, a3);
        size_t o = (size_t)n * C + lq * 4;
        f32x4 xv = __builtin_nontemporal_load((const f32x4*)(x + o));
        float fdg = (float)dg;
        f32x4 tv;
        tv.x = fdg * xv.x - a0;
        tv.y = fdg * xv.y - a1;
        tv.z = fdg * xv.z - a2;
        tv.w = fdg * xv.w - a3;
        __builtin_nontemporal_store(tv, (f32x4*)(t1 + o));
        uint2 r;
        r.x = f2bf(tv.x) | (f2bf(tv.y) << 16);
        r.y = f2bf(tv.z) | (f2bf(tv.w) << 16);
        t1b2[(size_t)n * 8 + lq] = r;
    }
    grid.sync();

    // ---- P4: matvec2 + final  y = w0*x + w1*t1 + w2*(deg*t1 - A@t1) ----
    float w0 = wts[0], w1 = wts[1], w2 = wts[2];
    for (int g = gid0; g < total; g += gthreads) {
        int n = g >> 3;
        int lq = g & 7;
        int rs = row_start[n];
        int dg = ideg[n];
        float a0 = 0.f, a1 = 0.f, a2 = 0.f, a3 = 0.f;
        accum_seg(t1b2, pk, rs, rs + dg, lq, a0, a1, a2, a3);
        size_t o = (size_t)n * C + lq * 4;
        f32x4 xv = __builtin_nontemporal_load((const f32x4*)(x + o));
        f32x4 tv = __builtin_nontemporal_load((const f32x4*)(t1 + o));
        float fdg = (float)dg;
        f32x4 r;
        r.x = w0 * xv.x + w1 * tv.x + w2 * (fdg * tv.x - a0);
        r.y = w0 * xv.y + w1 * tv.y + w2 * (fdg * tv.y - a1);
        r.z = w0 * xv.z + w1 * tv.z + w2 * (fdg * tv.z - a2);
        r.w = w0 * xv.w + w1 * tv.w + w2 * (fdg * tv.w - a3);
        __builtin_nontemporal_store(r, (f32x4*)(y + o));
    }
}

// ================= R7-proven fallback path =================
__global__ void init_cursor(int* __restrict__ cursor, int nbuck) {
    int i = blockIdx.x * blockDim.x + threadIdx.x;
    if (i < nbuck) cursor[i] = i * CAPC;
}

__global__ __launch_bounds__(1024) void phaseA(const int* __restrict__ src,
                                               const int* __restrict__ dst,
                                               int* __restrict__ cursor,
                                               int* __restrict__ pk,
                                               int E, int nbuck, int chunk) {
    extern __shared__ int l[];
    int* lcnt = l;
    int* lcur = l + nbuck;
    int tid = threadIdx.x;
    for (int i = tid; i < nbuck; i += 1024) lcnt[i] = 0;
    __syncthreads();
    int base = blockIdx.x * chunk;
    int end  = min(base + chunk, E);
    for (int e = base + tid; e < end; e += 1024)
        atomicAdd(&lcnt[dst[e] >> BSH], 1);
    __syncthreads();
    for (int i = tid; i < nbuck; i += 1024) {
        int c = lcnt[i];
        lcur[i] = c ? atomicAdd(&cursor[i], c) : 0;
    }
    __syncthreads();
    for (int e = base + tid; e < end; e += 1024) {
        int d = dst[e];
        int b = d >> BSH;
        int pos = atomicAdd(&lcur[b], 1);
        pk[pos] = src[e] | ((d & (BNODE - 1)) << 17);
    }
}

__global__ __launch_bounds__(512) void phaseB(int* __restrict__ pk,
                                              const int* __restrict__ cursor,
                                              int* __restrict__ row_start,
                                              int* __restrict__ ideg,
                                              const float* __restrict__ x,
                                              uint2* __restrict__ xb2, int N) {
    __shared__ int ent[CAPC];
    __shared__ int h[BNODE];
    __shared__ int s[BNODE];
    __shared__ int cur[BNODE];
    int b = blockIdx.x;
    int tid = threadIdx.x;
    int n0 = b << BSH;
    int nvalid = min(N - n0, BNODE);
    for (int i = tid; i < nvalid * 8; i += 512) {
        int n = n0 + (i >> 3);
        int lq = i & 7;
        const float* xp = x + (size_t)n * C + lq * 4;
        uint2 r;
        r.x = f2bf(xp[0]) | (f2bf(xp[1]) << 16);
        r.y = f2bf(xp[2]) | (f2bf(xp[3]) << 16);
        xb2[(size_t)n * 8 + lq] = r;
    }
    int base = b * CAPC;
    int cnt = min(cursor[b] - base, CAPC);
    for (int i = tid; i < cnt; i += 512) ent[i] = pk[base + i];
    if (tid < BNODE) h[tid] = 0;
    __syncthreads();
    for (int i = tid; i < cnt; i += 512) atomicAdd(&h[ent[i] >> 17], 1);
    __syncthreads();
    int v = 0;
    if (tid < BNODE) { v = h[tid]; s[tid] = v; }
    __syncthreads();
    for (int off = 1; off < BNODE; off <<= 1) {
        int u = 0;
        if (tid < BNODE && tid >= off) u = s[tid - off];
        __syncthreads();
        if (tid < BNODE) s[tid] += u;
        __syncthreads();
    }
    if (tid < BNODE) {
        int exc = s[tid] - v;
        int n = n0 + tid;
        if (n < N) { row_start[n] = base + exc; ideg[n] = v; }
        cur[tid] = exc;
    }
    __syncthreads();
    for (int i = tid; i < cnt; i += 512) {
        int en = ent[i];
        int pos = atomicAdd(&cur[en >> 17], 1);
        pk[base + pos] = en & SRCMASK;
    }
}

__global__ __launch_bounds__(NT) void gather1_bf(const float* __restrict__ x,
        const uint2* __restrict__ xb2, const int* __restrict__ pk,
        const int* __restrict__ row_start, const int* __restrict__ ideg,
        float* __restrict__ t1, uint2* __restrict__ t1b2, int N) {
    int g = blockIdx.x * blockDim.x + threadIdx.x;
    int n = g >> 3;
    if (n >= N) return;
    int lq = g & 7;
    int rs = row_start[n];
    int dg = ideg[n];
    float a0 = 0.f, a1 = 0.f, a2 = 0.f, a3 = 0.f;
    accum_seg(xb2, pk, rs, rs + dg, lq, a0, a1, a2, a3);
    size_t o = (size_t)n * C + lq * 4;
    f32x4 xv = __builtin_nontemporal_load((const f32x4*)(x + o));
    float fdg = (float)dg;
    f32x4 tv;
    tv.x = fdg * xv.x - a0;
    tv.y = fdg * xv.y - a1;
    tv.z = fdg * xv.z - a2;
    tv.w = fdg * xv.w - a3;
    __builtin_nontemporal_store(tv, (f32x4*)(t1 + o));
    uint2 r;
    r.x = f2bf(tv.x) | (f2bf(tv.y) << 16);
    r.y = f2bf(tv.z) | (f2bf(tv.w) << 16);
    t1b2[(size_t)n * 8 + lq] = r;
}

__global__ __launch_bounds__(NT) void gather2_bf(const float* __restrict__ x,
        const float* __restrict__ t1, const uint2* __restrict__ t1b2,
        const int* __restrict__ pk, const int* __restrict__ row_start,
        const int* __restrict__ ideg, const float* __restrict__ wts,
        float* __restrict__ y, int N) {
    int g = blockIdx.x * blockDim.x + threadIdx.x;
    int n = g >> 3;
    if (n >= N) return;
    int lq = g & 7;
    int rs = row_start[n];
    int dg = ideg[n];
    float a0 = 0.f, a1 = 0.f, a2 = 0.f, a3 = 0.f;
    accum_seg(t1b2, pk, rs, rs + dg, lq, a0, a1, a2, a3);
    size_t o = (size_t)n * C + lq * 4;
    f32x4 xv = __builtin_nontemporal_load((const f32x4*)(x + o));
    f32x4 tv = __builtin_nontemporal_load((const f32x4*)(t1 + o));
    float w0 = wts[0], w1 = wts[1], w2 = wts[2];
    float fdg = (float)dg;
    f32x4 r;
    r.x = w0 * xv.x + w1 * tv.x + w2 * (fdg * tv.x - a0);
    r.y = w0 * xv.y + w1 * tv.y + w2 * (fdg * tv.y - a1);
    r.z = w0 * xv.z + w1 * tv.z + w2 * (fdg * tv.z - a2);
    r.w = w0 * xv.w + w1 * tv.w + w2 * (fdg * tv.w - a3);
    __builtin_nontemporal_store(r, (f32x4*)(y + o));
}

extern "C" void kernel_launch(void* const* d_in, const int* in_sizes, int n_in,
                              void* d_out, int out_size, void* d_ws, size_t ws_size,
                              hipStream_t stream) {
    const float* x    = (const float*)d_in[0];
    const float* wts  = (const float*)d_in[1];
    const int*   esrc = (const int*)d_in[2];
    const int*   edst = (const int*)d_in[3];
    float*       y    = (float*)d_out;

    const int N = in_sizes[0] / C;                 // 100000
    const int E = in_sizes[2];                     // 1600000
    int nbuck = (N + BNODE - 1) >> BSH;            // 391
    const int nc = N * C;

    char* p = (char*)d_ws;
    auto align16 = [](size_t s) { return (s + 15) & ~(size_t)15; };
    int* cursor    = (int*)p; p += align16((size_t)nbuck * 4);
    int* row_start = (int*)p; p += align16((size_t)N * 4);
    int* ideg      = (int*)p; p += align16((size_t)N * 4);
    int* pk        = (int*)p; p += align16((size_t)nbuck * CAPC * 4);
    float* t1      = (float*)p; p += align16((size_t)nc * 4);
    uint2* xb2     = (uint2*)p; p += align16((size_t)nc * 2);
    uint2* t1b2    = (uint2*)p; p += align16((size_t)nc * 2);

    // ---- try the cooperative single-kernel path ----
    int maxB = 0;
    hipError_t qerr = hipOccupancyMaxActiveBlocksPerMultiprocessor(
        &maxB, (const void*)gcn_coop, NTC, 0);
    int NB = 0;
    if (qerr == hipSuccess && maxB > 0) {
        NB = maxB * 256;                 // MI355X: 256 CUs
        if (NB > 1024) NB = 1024;
    }
    bool launched = false;
    if (NB >= 256) {
        int chunk = (E + NB - 1) / NB;
        void* args[] = { (void*)&x, (void*)&esrc, (void*)&edst, (void*)&wts,
                         (void*)&y, (void*)&cursor, (void*)&row_start,
                         (void*)&ideg, (void*)&pk, (void*)&t1, (void*)&xb2,
                         (void*)&t1b2, (void*)&N, (void*)&E, (void*)&nbuck,
                         (void*)&chunk };
        hipError_t lerr = hipLaunchCooperativeKernel(
            (const void*)gcn_coop, dim3(NB), dim3(NTC), args, 0, stream);
        launched = (lerr == hipSuccess);
    }

    if (!launched) {
        // ---- R7-proven multi-kernel fallback ----
        init_cursor<<<(nbuck + NT - 1) / NT, NT, 0, stream>>>(cursor, nbuck);
        const int ABLK = 256;
        const int chunk = (E + ABLK - 1) / ABLK;
        const size_t lds_a = (size_t)nbuck * 2 * 4;
        phaseA<<<ABLK, 1024, lds_a, stream>>>(esrc, edst, cursor, pk, E, nbuck, chunk);
        phaseB<<<nbuck, 512, 0, stream>>>(pk, cursor, row_start, ideg, x, xb2, N);
        const int gblocks = ((size_t)N * 8 + NT - 1) / NT;
        gather1_bf<<<gblocks, NT, 0, stream>>>(x, xb2, pk, row_start, ideg, t1, t1b2, N);
        gather2_bf<<<gblocks, NT, 0, stream>>>(x, t1, t1b2, pk, row_start, ideg, wts, y, N);
    }
}

// Round 10
// 174.702 us; speedup vs baseline: 3.5672x; 3.5672x over previous
//
#include <hip/hip_runtime.h>

#define C 32
#define NT 256
#define BSH 8              // 256 nodes per bucket
#define BNODE 256
#define CAPC 5632          // per-bucket capacity (mean 4096, +24 sigma)
#define SRCMASK 0x1FFFF

typedef float f32x4 __attribute__((ext_vector_type(4)));

__device__ __forceinline__ unsigned int f2bf(float f) {
    unsigned int u = __float_as_uint(f);
    return (u + 0x7FFFu + ((u >> 16) & 1u)) >> 16;   // RNE to bf16
}
__device__ __forceinline__ float bflo(unsigned int u) { return __uint_as_float(u << 16); }
__device__ __forceinline__ float bfhi(unsigned int u) { return __uint_as_float(u & 0xFFFF0000u); }

// Phase A: bucketize by dst>>8. 512 blocks x 1024 threads (2 blk/CU) — R7's
// 256 blocks left the CUs 1/8 occupied during the latency-heavy scatter.
// cursor[] starts zeroed (memset); reservation adds bucket base explicitly.
__global__ __launch_bounds__(1024) void phaseA(const int* __restrict__ src,
                                               const int* __restrict__ dst,
                                               int* __restrict__ cursor,
                                               int* __restrict__ pk,
                                               int E, int nbuck, int chunk) {
    extern __shared__ int l[];          // lcnt[nbuck] | lcur[nbuck]
    int* lcnt = l;
    int* lcur = l + nbuck;
    int tid = threadIdx.x;
    for (int i = tid; i < nbuck; i += 1024) lcnt[i] = 0;
    __syncthreads();
    int base = blockIdx.x * chunk;
    int end  = min(base + chunk, E);
    for (int e = base + tid; e < end; e += 1024)
        atomicAdd(&lcnt[dst[e] >> BSH], 1);
    __syncthreads();
    for (int i = tid; i < nbuck; i += 1024) {
        int c = lcnt[i];
        lcur[i] = i * CAPC + (c ? atomicAdd(&cursor[i], c) : 0);
    }
    __syncthreads();
    for (int e = base + tid; e < end; e += 1024) {
        int d = dst[e];
        int b = d >> BSH;
        int pos = atomicAdd(&lcur[b], 1);
        pk[pos] = src[e] | ((d & (BNODE - 1)) << 17);
    }
}

// Phase B: per-bucket counting sort in place, 1024 threads, histogram fused
// into the staging load. Fused x->bf16 conversion of the bucket's own rows.
__global__ __launch_bounds__(1024) void phaseB(int* __restrict__ pk,
                                               const int* __restrict__ cursor,
                                               int* __restrict__ row_start,
                                               int* __restrict__ ideg,
                                               const float* __restrict__ x,
                                               uint2* __restrict__ xb2, int N) {
    __shared__ int ent[CAPC];
    __shared__ int h[BNODE];
    __shared__ int ss[BNODE];
    __shared__ int cur[BNODE];
    int b = blockIdx.x;
    int tid = threadIdx.x;

    if (tid < BNODE) h[tid] = 0;

    // fused cvt: bucket's own x rows -> packed bf16 (8 x uint2 per row)
    int n0 = b << BSH;
    int nvalid = min(N - n0, BNODE);
    for (int i = tid; i < nvalid * 8; i += 1024) {
        int n = n0 + (i >> 3);
        int lq = i & 7;
        const float* xp = x + (size_t)n * C + lq * 4;
        uint2 r;
        r.x = f2bf(xp[0]) | (f2bf(xp[1]) << 16);
        r.y = f2bf(xp[2]) | (f2bf(xp[3]) << 16);
        xb2[(size_t)n * 8 + lq] = r;
    }

    int base = b * CAPC;
    int cnt = min(cursor[b], CAPC);
    __syncthreads();                   // h zeroed before hist
    for (int i = tid; i < cnt; i += 1024) {
        int en = pk[base + i];
        ent[i] = en;
        atomicAdd(&h[en >> 17], 1);    // hist fused with staging load
    }
    __syncthreads();
    int v = 0;
    if (tid < BNODE) { v = h[tid]; ss[tid] = v; }
    __syncthreads();
    for (int off = 1; off < BNODE; off <<= 1) {
        int u = 0;
        if (tid < BNODE && tid >= off) u = ss[tid - off];
        __syncthreads();
        if (tid < BNODE) ss[tid] += u;
        __syncthreads();
    }
    if (tid < BNODE) {
        int exc = ss[tid] - v;
        int n = n0 + tid;
        if (n < N) { row_start[n] = base + exc; ideg[n] = v; }
        cur[tid] = exc;
    }
    __syncthreads();
    for (int i = tid; i < cnt; i += 1024) {
        int en = ent[i];
        int pos = atomicAdd(&cur[en >> 17], 1);
        pk[base + pos] = en & SRCMASK;
    }
}

// accumulate bf16 rows over pk[lo..hi) for lane-quarter lq (4 channels)
__device__ __forceinline__ void accum_seg(const uint2* __restrict__ arr,
                                          const int* __restrict__ pk,
                                          int lo, int hi, int lq,
                                          float& a0, float& a1, float& a2, float& a3) {
#define ACC4(ux, uy) { a0 += bflo(ux); a1 += bfhi(ux); a2 += bflo(uy); a3 += bfhi(uy); }
    int j = lo;
    for (; j + 7 < hi; j += 8) {
        int s0 = __builtin_nontemporal_load(&pk[j]);
        int s1 = __builtin_nontemporal_load(&pk[j + 1]);
        int s2 = __builtin_nontemporal_load(&pk[j + 2]);
        int s3 = __builtin_nontemporal_load(&pk[j + 3]);
        int s4 = __builtin_nontemporal_load(&pk[j + 4]);
        int s5 = __builtin_nontemporal_load(&pk[j + 5]);
        int s6 = __builtin_nontemporal_load(&pk[j + 6]);
        int s7 = __builtin_nontemporal_load(&pk[j + 7]);
        uint2 u0 = arr[(size_t)s0 * 8 + lq];
        uint2 u1 = arr[(size_t)s1 * 8 + lq];
        uint2 u2 = arr[(size_t)s2 * 8 + lq];
        uint2 u3 = arr[(size_t)s3 * 8 + lq];
        uint2 u4 = arr[(size_t)s4 * 8 + lq];
        uint2 u5 = arr[(size_t)s5 * 8 + lq];
        uint2 u6 = arr[(size_t)s6 * 8 + lq];
        uint2 u7 = arr[(size_t)s7 * 8 + lq];
        ACC4(u0.x, u0.y) ACC4(u1.x, u1.y) ACC4(u2.x, u2.y) ACC4(u3.x, u3.y)
        ACC4(u4.x, u4.y) ACC4(u5.x, u5.y) ACC4(u6.x, u6.y) ACC4(u7.x, u7.y)
    }
    for (; j + 1 < hi; j += 2) {
        int s0 = __builtin_nontemporal_load(&pk[j]);
        int s1 = __builtin_nontemporal_load(&pk[j + 1]);
        uint2 u0 = arr[(size_t)s0 * 8 + lq];
        uint2 u1 = arr[(size_t)s1 * 8 + lq];
        ACC4(u0.x, u0.y) ACC4(u1.x, u1.y)
    }
    if (j < hi) {
        uint2 u0 = arr[(size_t)__builtin_nontemporal_load(&pk[j]) * 8 + lq];
        ACC4(u0.x, u0.y)
    }
#undef ACC4
}

// ---- matvec1: t1b = bf16(deg*x - A@x). All-bf16; no fp32 t1 round-trip. ----
__global__ __launch_bounds__(NT) void gather1_bf(const uint2* __restrict__ xb2,
        const int* __restrict__ pk, const int* __restrict__ row_start,
        const int* __restrict__ ideg, uint2* __restrict__ t1b2, int N) {
    int g = blockIdx.x * blockDim.x + threadIdx.x;
    int n = g >> 3;
    if (n >= N) return;
    int lq = g & 7;
    int rs = row_start[n];
    int dg = ideg[n];
    float a0 = 0.f, a1 = 0.f, a2 = 0.f, a3 = 0.f;
    accum_seg(xb2, pk, rs, rs + dg, lq, a0, a1, a2, a3);
    uint2 xs = xb2[(size_t)n * 8 + lq];          // self row (sequential, coalesced)
    float fdg = (float)dg;
    float t0 = fdg * bflo(xs.x) - a0;
    float t1v = fdg * bfhi(xs.x) - a1;
    float t2 = fdg * bflo(xs.y) - a2;
    float t3 = fdg * bfhi(xs.y) - a3;
    uint2 r;
    r.x = f2bf(t0) | (f2bf(t1v) << 16);
    r.y = f2bf(t2) | (f2bf(t3) << 16);
    t1b2[(size_t)n * 8 + lq] = r;
}

// ---- matvec2 + final: y = w0*x + w1*t1 + w2*(deg*t1 - A@t1), self terms bf16 ----
__global__ __launch_bounds__(NT) void gather2_bf(const uint2* __restrict__ xb2,
        const uint2* __restrict__ t1b2, const int* __restrict__ pk,
        const int* __restrict__ row_start, const int* __restrict__ ideg,
        const float* __restrict__ wts, float* __restrict__ y, int N) {
    int g = blockIdx.x * blockDim.x + threadIdx.x;
    int n = g >> 3;
    if (n >= N) return;
    int lq = g & 7;
    int rs = row_start[n];
    int dg = ideg[n];
    float a0 = 0.f, a1 = 0.f, a2 = 0.f, a3 = 0.f;
    accum_seg(t1b2, pk, rs, rs + dg, lq, a0, a1, a2, a3);
    uint2 xs = xb2[(size_t)n * 8 + lq];
    uint2 ts = t1b2[(size_t)n * 8 + lq];
    float w0 = wts[0], w1 = wts[1], w2 = wts[2];
    float fdg = (float)dg;
    float tv0 = bflo(ts.x), tv1 = bfhi(ts.x), tv2 = bflo(ts.y), tv3 = bfhi(ts.y);
    f32x4 r;
    r.x = w0 * bflo(xs.x) + w1 * tv0 + w2 * (fdg * tv0 - a0);
    r.y = w0 * bfhi(xs.x) + w1 * tv1 + w2 * (fdg * tv1 - a1);
    r.z = w0 * bflo(xs.y) + w1 * tv2 + w2 * (fdg * tv2 - a2);
    r.w = w0 * bfhi(xs.y) + w1 * tv3 + w2 * (fdg * tv3 - a3);
    size_t o = (size_t)n * C + lq * 4;
    __builtin_nontemporal_store(r, (f32x4*)(y + o));
}

// ---- fp32 fallback (only if ws_size too small; R4-proven) ----
__global__ __launch_bounds__(NT) void gather1_f32(const float* __restrict__ x,
        const int* __restrict__ pk, const int* __restrict__ row_start,
        const int* __restrict__ ideg, float* __restrict__ t1, int N) {
    int g = blockIdx.x * blockDim.x + threadIdx.x;
    int n = g >> 5;
    if (n >= N) return;
    int ch = g & 31;
    int rs = row_start[n], dg = ideg[n], re = rs + dg;
    float a0 = 0, a1 = 0, a2 = 0, a3 = 0;
    int j = rs;
    for (; j + 3 < re; j += 4) {
        a0 += x[(size_t)pk[j] * C + ch];     a1 += x[(size_t)pk[j + 1] * C + ch];
        a2 += x[(size_t)pk[j + 2] * C + ch]; a3 += x[(size_t)pk[j + 3] * C + ch];
    }
    for (; j < re; ++j) a0 += x[(size_t)pk[j] * C + ch];
    size_t o = (size_t)n * C + ch;
    t1[o] = (float)dg * x[o] - ((a0 + a1) + (a2 + a3));
}
__global__ __launch_bounds__(NT) void gather2_f32(const float* __restrict__ x,
        const float* __restrict__ t1, const int* __restrict__ pk,
        const int* __restrict__ row_start, const int* __restrict__ ideg,
        const float* __restrict__ wts, float* __restrict__ y, int N) {
    int g = blockIdx.x * blockDim.x + threadIdx.x;
    int n = g >> 5;
    if (n >= N) return;
    int ch = g & 31;
    int rs = row_start[n], dg = ideg[n], re = rs + dg;
    float a0 = 0, a1 = 0, a2 = 0, a3 = 0;
    int j = rs;
    for (; j + 3 < re; j += 4) {
        a0 += t1[(size_t)pk[j] * C + ch];     a1 += t1[(size_t)pk[j + 1] * C + ch];
        a2 += t1[(size_t)pk[j + 2] * C + ch]; a3 += t1[(size_t)pk[j + 3] * C + ch];
    }
    for (; j < re; ++j) a0 += t1[(size_t)pk[j] * C + ch];
    size_t o = (size_t)n * C + ch;
    float tv = t1[o];
    y[o] = wts[0] * x[o] + wts[1] * tv + wts[2] * ((float)dg * tv - ((a0 + a1) + (a2 + a3)));
}

extern "C" void kernel_launch(void* const* d_in, const int* in_sizes, int n_in,
                              void* d_out, int out_size, void* d_ws, size_t ws_size,
                              hipStream_t stream) {
    const float* x    = (const float*)d_in[0];
    const float* wts  = (const float*)d_in[1];
    const int*   esrc = (const int*)d_in[2];
    const int*   edst = (const int*)d_in[3];
    float*       y    = (float*)d_out;

    const int N = in_sizes[0] / C;                 // 100000
    const int E = in_sizes[2];                     // 1600000
    const int nbuck = (N + BNODE - 1) >> BSH;      // 391
    const int nc = N * C;

    char* p = (char*)d_ws;
    auto align16 = [](size_t s) { return (s + 15) & ~(size_t)15; };
    int* cursor    = (int*)p; p += align16((size_t)nbuck * 4);
    int* row_start = (int*)p; p += align16((size_t)N * 4);
    int* ideg      = (int*)p; p += align16((size_t)N * 4);
    int* pk        = (int*)p; p += align16((size_t)nbuck * CAPC * 4);
    uint2* xb2     = (uint2*)p; p += align16((size_t)nc * 2);
    uint2* t1b2    = (uint2*)p; p += align16((size_t)nc * 2);
    float* t1      = (float*)p;                    // only used by fp32 fallback
    bool bf_ok = (size_t)(p - (char*)d_ws) <= ws_size;

    hipMemsetAsync(cursor, 0, (size_t)nbuck * 4, stream);

    const int ABLK = 512;                          // 2 blocks/CU during build
    const int chunk = (E + ABLK - 1) / ABLK;
    const size_t lds_a = (size_t)nbuck * 2 * 4;
    phaseA<<<ABLK, 1024, lds_a, stream>>>(esrc, edst, cursor, pk, E, nbuck, chunk);
    phaseB<<<nbuck, 1024, 0, stream>>>(pk, cursor, row_start, ideg, x, xb2, N);

    if (bf_ok) {
        const int gblocks = ((size_t)N * 8 + NT - 1) / NT;
        gather1_bf<<<gblocks, NT, 0, stream>>>(xb2, pk, row_start, ideg, t1b2, N);
        gather2_bf<<<gblocks, NT, 0, stream>>>(xb2, t1b2, pk, row_start, ideg, wts, y, N);
    } else {
        const int gblocks = ((size_t)N * 32 + NT - 1) / NT;
        gather1_f32<<<gblocks, NT, 0, stream>>>(x, pk, row_start, ideg, t1, N);
        gather2_f32<<<gblocks, NT, 0, stream>>>(x, t1, pk, row_start, ideg, wts, y, N);
    }
}